// Round 2
// baseline (654.997 us; speedup 1.0000x reference)
//
#include <hip/hip_runtime.h>
#include <math.h>

// ---- problem constants ----
// x: [8,1,512,512] fp32; patches 8x8 -> per batch 64x64 = 4096 patches, pdim=64
// HID=8, SCALE=8^-0.5. Output [8,512,512,3] fp32.
static constexpr float QSCALE = 0.35355339059327373f * 1.4426950408889634f; // SCALE * log2(e)

// =====================================================================
// Kernel 1: patchify + QKV projection (64 -> 8 x3)
// thread per patch; weights staged in LDS (broadcast reads)
// =====================================================================
__global__ __launch_bounds__(256) void qkv_kernel(
    const float* __restrict__ x,
    const float* __restrict__ Wq, const float* __restrict__ bq,
    const float* __restrict__ Wk, const float* __restrict__ bk,
    const float* __restrict__ Wv, const float* __restrict__ bv,
    float* __restrict__ Q, float* __restrict__ K, float* __restrict__ V)
{
    __shared__ float sW[64*24 + 24];
    for (int i = threadIdx.x; i < 64*24 + 24; i += 256) {
        float w;
        if (i < 1536) {
            int j = i / 24, c = i % 24;
            w = (c < 8) ? Wq[j*8 + c] : (c < 16) ? Wk[j*8 + (c-8)] : Wv[j*8 + (c-16)];
        } else {
            int c = i - 1536;
            w = (c < 8) ? bq[c] : (c < 16) ? bk[c-8] : bv[c-16];
        }
        sW[i] = w;
    }
    __syncthreads();

    int p = blockIdx.x * 256 + threadIdx.x;   // 0..32767 global patch id
    int b    = p >> 12;
    int pidx = p & 4095;
    int pr = pidx >> 6, pc = pidx & 63;
    const float* xb = x + ((size_t)(b*512 + pr*8)) * 512 + (size_t)pc*8;

    float px[64];
    #pragma unroll
    for (int i = 0; i < 8; ++i) {
        float4 a = *(const float4*)(xb + (size_t)i*512);
        float4 c = *(const float4*)(xb + (size_t)i*512 + 4);
        px[i*8+0]=a.x; px[i*8+1]=a.y; px[i*8+2]=a.z; px[i*8+3]=a.w;
        px[i*8+4]=c.x; px[i*8+5]=c.y; px[i*8+6]=c.z; px[i*8+7]=c.w;
    }
    float acc[24];
    #pragma unroll
    for (int o = 0; o < 24; ++o) acc[o] = sW[1536 + o];
    #pragma unroll
    for (int j = 0; j < 64; ++j) {
        float pj = px[j];
        #pragma unroll
        for (int o = 0; o < 24; ++o) acc[o] += pj * sW[j*24 + o];
    }
    size_t base = (size_t)p * 8;
    #pragma unroll
    for (int o = 0; o < 8; ++o) {
        Q[base+o] = acc[o];
        K[base+o] = acc[8+o];
        V[base+o] = acc[16+o];
    }
}

// =====================================================================
// Attention, chunked partial pass.
// lane = query (64 queries per wave), keys streamed WAVE-UNIFORMLY.
// Each lane keeps its own q[8], acc[8], lsum -> ~24 VGPR live state, no
// spill, no cross-lane epilogue. Key dim split into NC chunks for
// parallelism; unnormalized partials (lsum, acc) written per (q,chunk).
// Scores bounded (|s| small) -> no running max; exp2 domain with QSCALE
// folded into q at load.
// grid: 8 batches * 64 query-groups * NC chunks waves, 4 waves/block.
// =====================================================================
template<int NC>
__global__ __launch_bounds__(256) void attn_part_kernel(
    const float* __restrict__ Q, const float* __restrict__ K,
    const float* __restrict__ V,
    float* __restrict__ Pacc, float* __restrict__ Psum)
{
    constexpr int CH = 4096 / NC;   // keys per chunk
    int lane = threadIdx.x & 63;
    int wid  = threadIdx.x >> 6;
    int gw   = blockIdx.x * 4 + wid;       // 0 .. 8*64*NC-1
    int c  = gw % NC;                      // key chunk
    int t0 = gw / NC;
    int g  = t0 & 63;                      // query group (64 per batch)
    int b  = t0 >> 6;                      // batch

    // per-lane query
    const float* qp = Q + ((size_t)(b*4096 + g*64 + lane)) * 8;
    float q[8];
    {
        float4 a = ((const float4*)qp)[0];
        float4 d = ((const float4*)qp)[1];
        q[0]=a.x*QSCALE; q[1]=a.y*QSCALE; q[2]=a.z*QSCALE; q[3]=a.w*QSCALE;
        q[4]=d.x*QSCALE; q[5]=d.y*QSCALE; q[6]=d.z*QSCALE; q[7]=d.w*QSCALE;
    }

    float acc[8] = {0,0,0,0,0,0,0,0};
    float lsum = 0.f;

    // wave-uniform key/value stream over this chunk, 1-deep prefetch
    const float* kp = K + ((size_t)(b*4096 + c*CH)) * 8;
    const float* vp = V + ((size_t)(b*4096 + c*CH)) * 8;
    float4 k0 = ((const float4*)kp)[0], k1 = ((const float4*)kp)[1];
    float4 v0 = ((const float4*)vp)[0], v1 = ((const float4*)vp)[1];

    for (int j = 0; j < CH; ++j) {
        float4 nk0, nk1, nv0, nv1;
        if (j < CH-1) {
            nk0 = ((const float4*)(kp+8))[0];
            nk1 = ((const float4*)(kp+8))[1];
            nv0 = ((const float4*)(vp+8))[0];
            nv1 = ((const float4*)(vp+8))[1];
        }
        float s = q[0]*k0.x;
        s += q[1]*k0.y; s += q[2]*k0.z; s += q[3]*k0.w;
        s += q[4]*k1.x; s += q[5]*k1.y; s += q[6]*k1.z; s += q[7]*k1.w;
        float e = exp2f(s);
        lsum += e;
        acc[0] += e*v0.x; acc[1] += e*v0.y; acc[2] += e*v0.z; acc[3] += e*v0.w;
        acc[4] += e*v1.x; acc[5] += e*v1.y; acc[6] += e*v1.z; acc[7] += e*v1.w;
        kp += 8; vp += 8;
        k0 = nk0; k1 = nk1; v0 = nv0; v1 = nv1;
    }

    size_t qg = (size_t)(b*4096 + g*64 + lane);
    Psum[qg*NC + c] = lsum;
    float4* pa = (float4*)(Pacc + (qg*NC + c)*8);
    pa[0] = make_float4(acc[0], acc[1], acc[2], acc[3]);
    pa[1] = make_float4(acc[4], acc[5], acc[6], acc[7]);
}

// Reduce NC partials per query -> normalized output [32768 x 8]
template<int NC>
__global__ __launch_bounds__(256) void attn_reduce_kernel(
    const float* __restrict__ Pacc, const float* __restrict__ Psum,
    float* __restrict__ O)
{
    int qg = blockIdx.x * 256 + threadIdx.x;   // 0..32767
    float s = 0.f;
    float a[8] = {0,0,0,0,0,0,0,0};
    const float4* pa = (const float4*)(Pacc + (size_t)qg * NC * 8);
    #pragma unroll
    for (int c = 0; c < NC; ++c) {
        s += Psum[(size_t)qg*NC + c];
        float4 x0 = pa[c*2], x1 = pa[c*2+1];
        a[0]+=x0.x; a[1]+=x0.y; a[2]+=x0.z; a[3]+=x0.w;
        a[4]+=x1.x; a[5]+=x1.y; a[6]+=x1.z; a[7]+=x1.w;
    }
    float inv = 1.0f / s;
    float4* o = (float4*)(O + (size_t)qg * 8);
    o[0] = make_float4(a[0]*inv, a[1]*inv, a[2]*inv, a[3]*inv);
    o[1] = make_float4(a[4]*inv, a[5]*inv, a[6]*inv, a[7]*inv);
}

// =====================================================================
// Kernel 3: second-stage projection (8 -> 8 x3) from feats
// =====================================================================
__global__ __launch_bounds__(256) void proj2_kernel(
    const float* __restrict__ F,
    const float* __restrict__ Wsq, const float* __restrict__ bsq,
    const float* __restrict__ Wsk, const float* __restrict__ bsk,
    const float* __restrict__ Wsv, const float* __restrict__ bsv,
    float* __restrict__ Q, float* __restrict__ K, float* __restrict__ V)
{
    __shared__ float sW[8*24 + 24];
    for (int i = threadIdx.x; i < 8*24 + 24; i += 256) {
        float w;
        if (i < 192) {
            int j = i / 24, c = i % 24;
            w = (c < 8) ? Wsq[j*8 + c] : (c < 16) ? Wsk[j*8 + (c-8)] : Wsv[j*8 + (c-16)];
        } else {
            int c = i - 192;
            w = (c < 8) ? bsq[c] : (c < 16) ? bsk[c-8] : bsv[c-16];
        }
        sW[i] = w;
    }
    __syncthreads();

    int p = blockIdx.x * 256 + threadIdx.x;
    const float* f = F + (size_t)p * 8;
    float fv[8];
    {
        float4 a = ((const float4*)f)[0], c = ((const float4*)f)[1];
        fv[0]=a.x; fv[1]=a.y; fv[2]=a.z; fv[3]=a.w;
        fv[4]=c.x; fv[5]=c.y; fv[6]=c.z; fv[7]=c.w;
    }
    float acc[24];
    #pragma unroll
    for (int o = 0; o < 24; ++o) acc[o] = sW[192 + o];
    #pragma unroll
    for (int j = 0; j < 8; ++j) {
        float fj = fv[j];
        #pragma unroll
        for (int o = 0; o < 24; ++o) acc[o] += fj * sW[j*24 + o];
    }
    size_t base = (size_t)p * 8;
    #pragma unroll
    for (int o = 0; o < 8; ++o) {
        Q[base+o] = acc[o];
        K[base+o] = acc[8+o];
        V[base+o] = acc[16+o];
    }
}

// =====================================================================
// Kernel 5: LayerNorm(8) + proj to 3 + clamped softplus + 8x upsample
// thread per patch; writes 8 rows x 24 floats (float4-vectorized)
// =====================================================================
__global__ __launch_bounds__(256) void head_kernel(
    const float* __restrict__ S,
    const float* __restrict__ ln_w, const float* __restrict__ ln_b,
    const float* __restrict__ Wp, const float* __restrict__ bp,
    float* __restrict__ out)
{
    int p = blockIdx.x * 256 + threadIdx.x;
    int b    = p >> 12;
    int pidx = p & 4095;
    int pr = pidx >> 6, pc = pidx & 63;

    const float* s = S + (size_t)p * 8;
    float f[8];
    {
        float4 a = ((const float4*)s)[0], c = ((const float4*)s)[1];
        f[0]=a.x; f[1]=a.y; f[2]=a.z; f[3]=a.w;
        f[4]=c.x; f[5]=c.y; f[6]=c.z; f[7]=c.w;
    }
    float mu = 0.f;
    #pragma unroll
    for (int d = 0; d < 8; ++d) mu += f[d];
    mu *= 0.125f;
    float var = 0.f;
    #pragma unroll
    for (int d = 0; d < 8; ++d) { float t = f[d]-mu; var += t*t; }
    var *= 0.125f;
    float r = rsqrtf(var + 1e-5f);

    float o0 = bp[0], o1 = bp[1], o2 = bp[2];
    #pragma unroll
    for (int d = 0; d < 8; ++d) {
        float n = (f[d]-mu)*r*ln_w[d] + ln_b[d];
        o0 += n*Wp[d*3+0]; o1 += n*Wp[d*3+1]; o2 += n*Wp[d*3+2];
    }
    float o[3] = {o0, o1, o2};
    #pragma unroll
    for (int cix = 0; cix < 3; ++cix) {
        float xx = o[cix];
        float sp = fmaxf(xx, 0.f) + log1pf(expf(-fabsf(xx)));  // stable softplus
        o[cix] = fminf(sp, 6.0f) + 1e-6f;
    }

    float4 f40 = make_float4(o[0], o[1], o[2], o[0]);
    float4 f41 = make_float4(o[1], o[2], o[0], o[1]);
    float4 f42 = make_float4(o[2], o[0], o[1], o[2]);
    float* ob = out + (((size_t)(b*512 + pr*8)) * 512 + (size_t)pc*8) * 3;
    #pragma unroll
    for (int i = 0; i < 8; ++i) {
        float4* row = (float4*)(ob + (size_t)i * 512 * 3);
        row[0]=f40; row[1]=f41; row[2]=f42; row[3]=f40; row[4]=f41; row[5]=f42;
    }
}

// =====================================================================
extern "C" void kernel_launch(void* const* d_in, const int* in_sizes, int n_in,
                              void* d_out, int out_size, void* d_ws, size_t ws_size,
                              hipStream_t stream)
{
    const float* x   = (const float*)d_in[0];
    const float* Wq  = (const float*)d_in[1];
    const float* bq  = (const float*)d_in[2];
    const float* Wk  = (const float*)d_in[3];
    const float* bk  = (const float*)d_in[4];
    const float* Wv  = (const float*)d_in[5];
    const float* bv  = (const float*)d_in[6];
    const float* Wsq = (const float*)d_in[7];
    const float* bsq = (const float*)d_in[8];
    const float* Wsk = (const float*)d_in[9];
    const float* bsk = (const float*)d_in[10];
    const float* Wsv = (const float*)d_in[11];
    const float* bsv = (const float*)d_in[12];
    const float* lnw = (const float*)d_in[13];
    const float* lnb = (const float*)d_in[14];
    const float* Wp  = (const float*)d_in[15];
    const float* bp  = (const float*)d_in[16];
    float* out = (float*)d_out;

    // workspace layout (floats):
    // A,B,C: QKV buffers (262144 each = 1 MB) ; D: feats/sig (1 MB)
    // Pacc: 32768*NC*8 ; Psum: 32768*NC
    float* A = (float*)d_ws;
    float* B = A + 262144;
    float* C = B + 262144;
    float* D = C + 262144;
    float* Pacc = D + 262144;

    qkv_kernel<<<128, 256, 0, stream>>>(x, Wq, bq, Wk, bk, Wv, bv, A, B, C);

    size_t need16 = (size_t)(4*262144 + 32768*16*8 + 32768*16) * 4;
    size_t need8  = (size_t)(4*262144 + 32768*8*8  + 32768*8 ) * 4;

    if (ws_size >= need16) {
        constexpr int NC = 16;
        float* Psum = Pacc + 32768*NC*8;
        attn_part_kernel<NC><<<128*NC, 256, 0, stream>>>(A, B, C, Pacc, Psum);
        attn_reduce_kernel<NC><<<128, 256, 0, stream>>>(Pacc, Psum, D);
        proj2_kernel<<<128, 256, 0, stream>>>(D, Wsq, bsq, Wsk, bsk, Wsv, bsv, A, B, C);
        attn_part_kernel<NC><<<128*NC, 256, 0, stream>>>(A, B, C, Pacc, Psum);
        attn_reduce_kernel<NC><<<128, 256, 0, stream>>>(Pacc, Psum, D);
    } else if (ws_size >= need8) {
        constexpr int NC = 8;
        float* Psum = Pacc + 32768*NC*8;
        attn_part_kernel<NC><<<128*NC, 256, 0, stream>>>(A, B, C, Pacc, Psum);
        attn_reduce_kernel<NC><<<128, 256, 0, stream>>>(Pacc, Psum, D);
        proj2_kernel<<<128, 256, 0, stream>>>(D, Wsq, bsq, Wsk, bsk, Wsv, bsv, A, B, C);
        attn_part_kernel<NC><<<128*NC, 256, 0, stream>>>(A, B, C, Pacc, Psum);
        attn_reduce_kernel<NC><<<128, 256, 0, stream>>>(Pacc, Psum, D);
    } else {
        constexpr int NC = 4;
        float* Psum = Pacc + 32768*NC*8;
        attn_part_kernel<NC><<<128*NC, 256, 0, stream>>>(A, B, C, Pacc, Psum);
        attn_reduce_kernel<NC><<<128, 256, 0, stream>>>(Pacc, Psum, D);
        proj2_kernel<<<128, 256, 0, stream>>>(D, Wsq, bsq, Wsk, bsk, Wsv, bsv, A, B, C);
        attn_part_kernel<NC><<<128*NC, 256, 0, stream>>>(A, B, C, Pacc, Psum);
        attn_reduce_kernel<NC><<<128, 256, 0, stream>>>(Pacc, Psum, D);
    }

    head_kernel<<<128, 256, 0, stream>>>(D, lnw, lnb, Wp, bp, out);
}

// Round 5
// 328.624 us; speedup vs baseline: 1.9932x; 1.9932x over previous
//
#include <hip/hip_runtime.h>
#include <math.h>

// ---- problem constants ----
// x: [8,1,512,512] fp32; patches 8x8 -> per batch 64x64 = 4096 patches, pdim=64
// HID=8, SCALE=8^-0.5. Output [8,512,512,3] fp32.
static constexpr float QSCALE = 0.35355339059327373f * 1.4426950408889634f; // SCALE * log2(e)

// =====================================================================
// Kernel 1: patchify + QKV projection (64 -> 8 x3)
// =====================================================================
__global__ __launch_bounds__(256) void qkv_kernel(
    const float* __restrict__ x,
    const float* __restrict__ Wq, const float* __restrict__ bq,
    const float* __restrict__ Wk, const float* __restrict__ bk,
    const float* __restrict__ Wv, const float* __restrict__ bv,
    float* __restrict__ Q, float* __restrict__ K, float* __restrict__ V)
{
    __shared__ float sW[64*24 + 24];
    for (int i = threadIdx.x; i < 64*24 + 24; i += 256) {
        float w;
        if (i < 1536) {
            int j = i / 24, c = i % 24;
            w = (c < 8) ? Wq[j*8 + c] : (c < 16) ? Wk[j*8 + (c-8)] : Wv[j*8 + (c-16)];
        } else {
            int c = i - 1536;
            w = (c < 8) ? bq[c] : (c < 16) ? bk[c-8] : bv[c-16];
        }
        sW[i] = w;
    }
    __syncthreads();

    int p = blockIdx.x * 256 + threadIdx.x;   // 0..32767 global patch id
    int b    = p >> 12;
    int pidx = p & 4095;
    int pr = pidx >> 6, pc = pidx & 63;
    const float* xb = x + ((size_t)(b*512 + pr*8)) * 512 + (size_t)pc*8;

    float px[64];
    #pragma unroll
    for (int i = 0; i < 8; ++i) {
        float4 a = *(const float4*)(xb + (size_t)i*512);
        float4 c = *(const float4*)(xb + (size_t)i*512 + 4);
        px[i*8+0]=a.x; px[i*8+1]=a.y; px[i*8+2]=a.z; px[i*8+3]=a.w;
        px[i*8+4]=c.x; px[i*8+5]=c.y; px[i*8+6]=c.z; px[i*8+7]=c.w;
    }
    float acc[24];
    #pragma unroll
    for (int o = 0; o < 24; ++o) acc[o] = sW[1536 + o];
    #pragma unroll
    for (int j = 0; j < 64; ++j) {
        float pj = px[j];
        #pragma unroll
        for (int o = 0; o < 24; ++o) acc[o] += pj * sW[j*24 + o];
    }
    size_t base = (size_t)p * 8;
    #pragma unroll
    for (int o = 0; o < 8; ++o) {
        Q[base+o] = acc[o];
        K[base+o] = acc[8+o];
        V[base+o] = acc[16+o];
    }
}

// =====================================================================
// Attention partial pass, v3.
// lane = query, NQ=4 queries per thread (amortizes K/V reads 4x).
// K/V streamed through double-buffered LDS tiles (T=64 keys, 8 KB),
// staged with fully coalesced float4 loads; compute reads are
// wave-uniform ds_read_b128 -> broadcast, conflict-free.
// Key dim split into NC chunks; unnormalized partials written as
// Pacc[c][qg][8], Psum[c][qg] (coalesced both on write and on reduce).
// Block: 256 threads = 1024 queries. Grid: 8 * 4 * NC blocks.
// =====================================================================
template<int NC>
__global__ __launch_bounds__(256) void attn_part_kernel(
    const float* __restrict__ Q, const float* __restrict__ K,
    const float* __restrict__ V,
    float* __restrict__ Pacc, float* __restrict__ Psum)
{
    constexpr int NQ = 4;
    constexpr int QB = 256 * NQ;          // 1024 queries per block
    constexpr int QGB = 4096 / QB;        // 4 query groups per batch
    constexpr int CH = 4096 / NC;         // keys per chunk
    constexpr int T  = 64;                // keys per LDS tile
    constexpr int NT = CH / T;            // tiles per chunk

    __shared__ float4 kv[2][T][4];        // [buf][key][{k0,k1,v0,v1}]  8 KB

    int tid = threadIdx.x;
    int blk = blockIdx.x;
    int c  = blk % NC;
    int t0 = blk / NC;
    int g  = t0 % QGB;
    int b  = t0 / QGB;

    const float4* Qb = (const float4*)(Q + ((size_t)b*4096 + g*QB) * 8);
    const float4* Kb = (const float4*)(K + (size_t)b*4096*8);
    const float4* Vb = (const float4*)(V + (size_t)b*4096*8);

    float q[NQ][8], acc[NQ][8], lsum[NQ];
    #pragma unroll
    for (int i = 0; i < NQ; ++i) {
        float4 a = Qb[(i*256 + tid)*2];
        float4 d = Qb[(i*256 + tid)*2 + 1];
        q[i][0]=a.x*QSCALE; q[i][1]=a.y*QSCALE; q[i][2]=a.z*QSCALE; q[i][3]=a.w*QSCALE;
        q[i][4]=d.x*QSCALE; q[i][5]=d.y*QSCALE; q[i][6]=d.z*QSCALE; q[i][7]=d.w*QSCALE;
        lsum[i] = 0.f;
        #pragma unroll
        for (int d2 = 0; d2 < 8; ++d2) acc[i][d2] = 0.f;
    }

    const int k0 = c * CH;   // first key of this chunk

    // cooperative stage: threads 0..127 load K tile, 128..255 load V tile
    auto stage = [&](int buf, int kt) {
        if (tid < 128) {
            int key = tid >> 1, part = tid & 1;
            kv[buf][key][part] = Kb[(kt + key)*2 + part];
        } else {
            int t2 = tid - 128;
            int key = t2 >> 1, part = t2 & 1;
            kv[buf][key][2 + part] = Vb[(kt + key)*2 + part];
        }
    };

    stage(0, k0);
    __syncthreads();

    for (int t = 0; t < NT; ++t) {
        if (t + 1 < NT) stage((t + 1) & 1, k0 + (t + 1) * T);
        int buf = t & 1;
        #pragma unroll 4
        for (int j = 0; j < T; ++j) {
            float4 kk0 = kv[buf][j][0], kk1 = kv[buf][j][1];
            float4 vv0 = kv[buf][j][2], vv1 = kv[buf][j][3];
            #pragma unroll
            for (int qi = 0; qi < NQ; ++qi) {
                float s = q[qi][0]*kk0.x;
                s += q[qi][1]*kk0.y; s += q[qi][2]*kk0.z; s += q[qi][3]*kk0.w;
                s += q[qi][4]*kk1.x; s += q[qi][5]*kk1.y; s += q[qi][6]*kk1.z; s += q[qi][7]*kk1.w;
                float e = exp2f(s);
                lsum[qi] += e;
                acc[qi][0] += e*vv0.x; acc[qi][1] += e*vv0.y; acc[qi][2] += e*vv0.z; acc[qi][3] += e*vv0.w;
                acc[qi][4] += e*vv1.x; acc[qi][5] += e*vv1.y; acc[qi][6] += e*vv1.z; acc[qi][7] += e*vv1.w;
            }
        }
        __syncthreads();
    }

    // partials: layout [chunk][query][...] for coalesced write + reduce
    #pragma unroll
    for (int i = 0; i < NQ; ++i) {
        size_t qg = (size_t)b*4096 + g*QB + i*256 + tid;
        Psum[(size_t)c*32768 + qg] = lsum[i];
        float4* pa = (float4*)(Pacc + ((size_t)c*32768 + qg)*8);
        pa[0] = make_float4(acc[i][0], acc[i][1], acc[i][2], acc[i][3]);
        pa[1] = make_float4(acc[i][4], acc[i][5], acc[i][6], acc[i][7]);
    }
}

// Reduce NC partials per query -> normalized output [32768 x 8]
template<int NC>
__global__ __launch_bounds__(256) void attn_reduce_kernel(
    const float* __restrict__ Pacc, const float* __restrict__ Psum,
    float* __restrict__ O)
{
    int qg = blockIdx.x * 256 + threadIdx.x;   // 0..32767
    float s = 0.f;
    float a[8] = {0,0,0,0,0,0,0,0};
    #pragma unroll
    for (int c = 0; c < NC; ++c) {
        s += Psum[(size_t)c*32768 + qg];
        const float4* pa = (const float4*)(Pacc + ((size_t)c*32768 + qg)*8);
        float4 x0 = pa[0], x1 = pa[1];
        a[0]+=x0.x; a[1]+=x0.y; a[2]+=x0.z; a[3]+=x0.w;
        a[4]+=x1.x; a[5]+=x1.y; a[6]+=x1.z; a[7]+=x1.w;
    }
    float inv = 1.0f / s;
    float4* o = (float4*)(O + (size_t)qg * 8);
    o[0] = make_float4(a[0]*inv, a[1]*inv, a[2]*inv, a[3]*inv);
    o[1] = make_float4(a[4]*inv, a[5]*inv, a[6]*inv, a[7]*inv);
}

// =====================================================================
// Kernel 3: second-stage projection (8 -> 8 x3) from feats
// =====================================================================
__global__ __launch_bounds__(256) void proj2_kernel(
    const float* __restrict__ F,
    const float* __restrict__ Wsq, const float* __restrict__ bsq,
    const float* __restrict__ Wsk, const float* __restrict__ bsk,
    const float* __restrict__ Wsv, const float* __restrict__ bsv,
    float* __restrict__ Q, float* __restrict__ K, float* __restrict__ V)
{
    __shared__ float sW[8*24 + 24];
    for (int i = threadIdx.x; i < 8*24 + 24; i += 256) {
        float w;
        if (i < 192) {
            int j = i / 24, c = i % 24;
            w = (c < 8) ? Wsq[j*8 + c] : (c < 16) ? Wsk[j*8 + (c-8)] : Wsv[j*8 + (c-16)];
        } else {
            int c = i - 192;
            w = (c < 8) ? bsq[c] : (c < 16) ? bsk[c-8] : bsv[c-16];
        }
        sW[i] = w;
    }
    __syncthreads();

    int p = blockIdx.x * 256 + threadIdx.x;
    const float* f = F + (size_t)p * 8;
    float fv[8];
    {
        float4 a = ((const float4*)f)[0], c = ((const float4*)f)[1];
        fv[0]=a.x; fv[1]=a.y; fv[2]=a.z; fv[3]=a.w;
        fv[4]=c.x; fv[5]=c.y; fv[6]=c.z; fv[7]=c.w;
    }
    float acc[24];
    #pragma unroll
    for (int o = 0; o < 24; ++o) acc[o] = sW[192 + o];
    #pragma unroll
    for (int j = 0; j < 8; ++j) {
        float fj = fv[j];
        #pragma unroll
        for (int o = 0; o < 24; ++o) acc[o] += fj * sW[j*24 + o];
    }
    size_t base = (size_t)p * 8;
    #pragma unroll
    for (int o = 0; o < 8; ++o) {
        Q[base+o] = acc[o];
        K[base+o] = acc[8+o];
        V[base+o] = acc[16+o];
    }
}

// =====================================================================
// Kernel 5: LayerNorm(8) + proj to 3 + clamped softplus + 8x upsample
// thread per (patch, row-pair): 4 threads share a patch -> 512 blocks
// =====================================================================
__global__ __launch_bounds__(256) void head_kernel(
    const float* __restrict__ S,
    const float* __restrict__ ln_w, const float* __restrict__ ln_b,
    const float* __restrict__ Wp, const float* __restrict__ bp,
    float* __restrict__ out)
{
    int idx = blockIdx.x * 256 + threadIdx.x;   // 0..131071
    int p  = idx >> 2;
    int rq = idx & 3;          // row pair 0..3 -> rows rq*2, rq*2+1
    int b    = p >> 12;
    int pidx = p & 4095;
    int pr = pidx >> 6, pc = pidx & 63;

    const float* s = S + (size_t)p * 8;
    float f[8];
    {
        float4 a = ((const float4*)s)[0], c = ((const float4*)s)[1];
        f[0]=a.x; f[1]=a.y; f[2]=a.z; f[3]=a.w;
        f[4]=c.x; f[5]=c.y; f[6]=c.z; f[7]=c.w;
    }
    float mu = 0.f;
    #pragma unroll
    for (int d = 0; d < 8; ++d) mu += f[d];
    mu *= 0.125f;
    float var = 0.f;
    #pragma unroll
    for (int d = 0; d < 8; ++d) { float t = f[d]-mu; var += t*t; }
    var *= 0.125f;
    float r = rsqrtf(var + 1e-5f);

    float o0 = bp[0], o1 = bp[1], o2 = bp[2];
    #pragma unroll
    for (int d = 0; d < 8; ++d) {
        float n = (f[d]-mu)*r*ln_w[d] + ln_b[d];
        o0 += n*Wp[d*3+0]; o1 += n*Wp[d*3+1]; o2 += n*Wp[d*3+2];
    }
    float o[3] = {o0, o1, o2};
    #pragma unroll
    for (int cix = 0; cix < 3; ++cix) {
        float xx = o[cix];
        float sp = fmaxf(xx, 0.f) + log1pf(expf(-fabsf(xx)));  // stable softplus
        o[cix] = fminf(sp, 6.0f) + 1e-6f;
    }

    float4 f40 = make_float4(o[0], o[1], o[2], o[0]);
    float4 f41 = make_float4(o[1], o[2], o[0], o[1]);
    float4 f42 = make_float4(o[2], o[0], o[1], o[2]);
    float* ob = out + (((size_t)(b*512 + pr*8 + rq*2)) * 512 + (size_t)pc*8) * 3;
    #pragma unroll
    for (int i = 0; i < 2; ++i) {
        float4* row = (float4*)(ob + (size_t)i * 512 * 3);
        row[0]=f40; row[1]=f41; row[2]=f42; row[3]=f40; row[4]=f41; row[5]=f42;
    }
}

// =====================================================================
extern "C" void kernel_launch(void* const* d_in, const int* in_sizes, int n_in,
                              void* d_out, int out_size, void* d_ws, size_t ws_size,
                              hipStream_t stream)
{
    const float* x   = (const float*)d_in[0];
    const float* Wq  = (const float*)d_in[1];
    const float* bq  = (const float*)d_in[2];
    const float* Wk  = (const float*)d_in[3];
    const float* bk  = (const float*)d_in[4];
    const float* Wv  = (const float*)d_in[5];
    const float* bv  = (const float*)d_in[6];
    const float* Wsq = (const float*)d_in[7];
    const float* bsq = (const float*)d_in[8];
    const float* Wsk = (const float*)d_in[9];
    const float* bsk = (const float*)d_in[10];
    const float* Wsv = (const float*)d_in[11];
    const float* bsv = (const float*)d_in[12];
    const float* lnw = (const float*)d_in[13];
    const float* lnb = (const float*)d_in[14];
    const float* Wp  = (const float*)d_in[15];
    const float* bp  = (const float*)d_in[16];
    float* out = (float*)d_out;

    // workspace layout (floats):
    // A,B,C: QKV buffers (262144 each = 1 MB) ; D: feats/sig (1 MB)
    // Pacc: 32768*NC*8 ; Psum: 32768*NC
    float* A = (float*)d_ws;
    float* B = A + 262144;
    float* C = B + 262144;
    float* D = C + 262144;
    float* Pacc = D + 262144;

    qkv_kernel<<<128, 256, 0, stream>>>(x, Wq, bq, Wk, bk, Wv, bv, A, B, C);

    size_t need16 = (size_t)(4*262144 + 32768*16*8 + 32768*16) * 4;

    if (ws_size >= need16) {
        constexpr int NC = 16;
        float* Psum = Pacc + (size_t)32768*NC*8;
        attn_part_kernel<NC><<<8*4*NC, 256, 0, stream>>>(A, B, C, Pacc, Psum);
        attn_reduce_kernel<NC><<<128, 256, 0, stream>>>(Pacc, Psum, D);
        proj2_kernel<<<128, 256, 0, stream>>>(D, Wsq, bsq, Wsk, bsk, Wsv, bsv, A, B, C);
        attn_part_kernel<NC><<<8*4*NC, 256, 0, stream>>>(A, B, C, Pacc, Psum);
        attn_reduce_kernel<NC><<<128, 256, 0, stream>>>(Pacc, Psum, D);
    } else {
        constexpr int NC = 8;
        float* Psum = Pacc + (size_t)32768*NC*8;
        attn_part_kernel<NC><<<8*4*NC, 256, 0, stream>>>(A, B, C, Pacc, Psum);
        attn_reduce_kernel<NC><<<128, 256, 0, stream>>>(Pacc, Psum, D);
        proj2_kernel<<<128, 256, 0, stream>>>(D, Wsq, bsq, Wsk, bsk, Wsv, bsv, A, B, C);
        attn_part_kernel<NC><<<8*4*NC, 256, 0, stream>>>(A, B, C, Pacc, Psum);
        attn_reduce_kernel<NC><<<128, 256, 0, stream>>>(Pacc, Psum, D);
    }

    head_kernel<<<512, 256, 0, stream>>>(D, lnw, lnb, Wp, bp, out);
}

// Round 6
// 322.927 us; speedup vs baseline: 2.0283x; 1.0176x over previous
//
#include <hip/hip_runtime.h>
#include <math.h>

// ---- problem constants ----
// x: [8,1,512,512] fp32; patches 8x8 -> per batch 64x64 = 4096 patches, pdim=64
// HID=8, SCALE=8^-0.5. Output [8,512,512,3] fp32.
static constexpr float QSCALE = 0.35355339059327373f * 1.4426950408889634f; // SCALE * log2(e)

// =====================================================================
// Kernel 1: patchify + QKV projection (64 -> 8 x3)
// v2: interleave row loads with FMAs -> ~45 live VGPRs (was ~95)
// =====================================================================
__global__ __launch_bounds__(256) void qkv_kernel(
    const float* __restrict__ x,
    const float* __restrict__ Wq, const float* __restrict__ bq,
    const float* __restrict__ Wk, const float* __restrict__ bk,
    const float* __restrict__ Wv, const float* __restrict__ bv,
    float* __restrict__ Q, float* __restrict__ K, float* __restrict__ V)
{
    __shared__ float sW[64*24 + 24];
    for (int i = threadIdx.x; i < 64*24 + 24; i += 256) {
        float w;
        if (i < 1536) {
            int j = i / 24, c = i % 24;
            w = (c < 8) ? Wq[j*8 + c] : (c < 16) ? Wk[j*8 + (c-8)] : Wv[j*8 + (c-16)];
        } else {
            int c = i - 1536;
            w = (c < 8) ? bq[c] : (c < 16) ? bk[c-8] : bv[c-16];
        }
        sW[i] = w;
    }
    __syncthreads();

    int p = blockIdx.x * 256 + threadIdx.x;   // 0..32767 global patch id
    int b    = p >> 12;
    int pidx = p & 4095;
    int pr = pidx >> 6, pc = pidx & 63;
    const float* xb = x + ((size_t)(b*512 + pr*8)) * 512 + (size_t)pc*8;

    float acc[24];
    #pragma unroll
    for (int o = 0; o < 24; ++o) acc[o] = sW[1536 + o];

    #pragma unroll
    for (int i = 0; i < 8; ++i) {
        float4 a = *(const float4*)(xb + (size_t)i*512);
        float4 c = *(const float4*)(xb + (size_t)i*512 + 4);
        float px[8] = {a.x, a.y, a.z, a.w, c.x, c.y, c.z, c.w};
        #pragma unroll
        for (int jj = 0; jj < 8; ++jj) {
            float pj = px[jj];
            const float* w = &sW[(i*8 + jj)*24];
            #pragma unroll
            for (int o = 0; o < 24; ++o) acc[o] += pj * w[o];
        }
    }
    size_t base = (size_t)p * 8;
    #pragma unroll
    for (int o = 0; o < 8; ++o) {
        Q[base+o] = acc[o];
        K[base+o] = acc[8+o];
        V[base+o] = acc[16+o];
    }
}

// =====================================================================
// Attention partial pass, v4.
// lane = query, NQ=4 queries per thread; K/V via static double-buffered
// LDS tiles (broadcast ds_read_b128). __launch_bounds__(256,2) gives the
// allocator a 256-VGPR budget so q/acc/kv live fully in VGPRs (v3's 64
// VGPR cap caused AGPR shuffling = 2.6x VALU instruction bloat).
// Key dim split into NC chunks; unnormalized partials per (chunk,query).
// Block: 256 threads = 1024 queries. Grid: 8 * 4 * NC blocks.
// =====================================================================
template<int NC>
__global__ __launch_bounds__(256, 2) void attn_part_kernel(
    const float* __restrict__ Q, const float* __restrict__ K,
    const float* __restrict__ V,
    float* __restrict__ Pacc, float* __restrict__ Psum)
{
    constexpr int NQ = 4;
    constexpr int QB = 256 * NQ;          // 1024 queries per block
    constexpr int QGB = 4096 / QB;        // 4 query groups per batch
    constexpr int CH = 4096 / NC;         // keys per chunk
    constexpr int T  = 64;                // keys per LDS tile
    constexpr int NT = CH / T;            // tiles per chunk (even for NC<=32)

    __shared__ float4 kvA[T][4];          // [key][{k0,k1,v0,v1}] 4 KB each
    __shared__ float4 kvB[T][4];

    int tid = threadIdx.x;
    int blk = blockIdx.x;
    int c  = blk % NC;
    int t0 = blk / NC;
    int g  = t0 % QGB;
    int b  = t0 / QGB;

    const float4* Qb = (const float4*)(Q + ((size_t)b*4096 + g*QB) * 8);
    const float4* Kb = (const float4*)(K + (size_t)b*4096*8);
    const float4* Vb = (const float4*)(V + (size_t)b*4096*8);

    float q[NQ][8], acc[NQ][8], lsum[NQ];
    #pragma unroll
    for (int i = 0; i < NQ; ++i) {
        float4 a = Qb[(i*256 + tid)*2];
        float4 d = Qb[(i*256 + tid)*2 + 1];
        q[i][0]=a.x*QSCALE; q[i][1]=a.y*QSCALE; q[i][2]=a.z*QSCALE; q[i][3]=a.w*QSCALE;
        q[i][4]=d.x*QSCALE; q[i][5]=d.y*QSCALE; q[i][6]=d.z*QSCALE; q[i][7]=d.w*QSCALE;
        lsum[i] = 0.f;
        #pragma unroll
        for (int d2 = 0; d2 < 8; ++d2) acc[i][d2] = 0.f;
    }

    const int k0 = c * CH;   // first key of this chunk

    // cooperative stage: threads 0..127 load K tile, 128..255 load V tile
    auto stage = [&](float4 (*kv)[4], int kt) {
        if (tid < 128) {
            int key = tid >> 1, part = tid & 1;
            kv[key][part] = Kb[(kt + key)*2 + part];
        } else {
            int t2 = tid - 128;
            int key = t2 >> 1, part = t2 & 1;
            kv[key][2 + part] = Vb[(kt + key)*2 + part];
        }
    };

    auto compute = [&](const float4 (*kv)[4]) {
        #pragma unroll 4
        for (int j = 0; j < T; ++j) {
            float4 kk0 = kv[j][0], kk1 = kv[j][1];
            float4 vv0 = kv[j][2], vv1 = kv[j][3];
            #pragma unroll
            for (int qi = 0; qi < NQ; ++qi) {
                float s = q[qi][0]*kk0.x;
                s += q[qi][1]*kk0.y; s += q[qi][2]*kk0.z; s += q[qi][3]*kk0.w;
                s += q[qi][4]*kk1.x; s += q[qi][5]*kk1.y; s += q[qi][6]*kk1.z; s += q[qi][7]*kk1.w;
                float e = exp2f(s);
                lsum[qi] += e;
                acc[qi][0] += e*vv0.x; acc[qi][1] += e*vv0.y; acc[qi][2] += e*vv0.z; acc[qi][3] += e*vv0.w;
                acc[qi][4] += e*vv1.x; acc[qi][5] += e*vv1.y; acc[qi][6] += e*vv1.z; acc[qi][7] += e*vv1.w;
            }
        }
    };

    stage(kvA, k0);
    __syncthreads();

    for (int t = 0; t < NT; t += 2) {
        if (t + 1 < NT) stage(kvB, k0 + (t + 1) * T);
        compute(kvA);
        __syncthreads();
        if (t + 2 < NT) stage(kvA, k0 + (t + 2) * T);
        if (t + 1 < NT) compute(kvB);
        __syncthreads();
    }

    // partials: layout [chunk][query][...] for coalesced write + reduce
    #pragma unroll
    for (int i = 0; i < NQ; ++i) {
        size_t qg = (size_t)b*4096 + g*QB + i*256 + tid;
        Psum[(size_t)c*32768 + qg] = lsum[i];
        float4* pa = (float4*)(Pacc + ((size_t)c*32768 + qg)*8);
        pa[0] = make_float4(acc[i][0], acc[i][1], acc[i][2], acc[i][3]);
        pa[1] = make_float4(acc[i][4], acc[i][5], acc[i][6], acc[i][7]);
    }
}

// Reduce NC partials per query -> normalized output [32768 x 8]
template<int NC>
__global__ __launch_bounds__(256) void attn_reduce_kernel(
    const float* __restrict__ Pacc, const float* __restrict__ Psum,
    float* __restrict__ O)
{
    int qg = blockIdx.x * 256 + threadIdx.x;   // 0..32767
    float s = 0.f;
    float a[8] = {0,0,0,0,0,0,0,0};
    #pragma unroll
    for (int c = 0; c < NC; ++c) {
        s += Psum[(size_t)c*32768 + qg];
        const float4* pa = (const float4*)(Pacc + ((size_t)c*32768 + qg)*8);
        float4 x0 = pa[0], x1 = pa[1];
        a[0]+=x0.x; a[1]+=x0.y; a[2]+=x0.z; a[3]+=x0.w;
        a[4]+=x1.x; a[5]+=x1.y; a[6]+=x1.z; a[7]+=x1.w;
    }
    float inv = 1.0f / s;
    float4* o = (float4*)(O + (size_t)qg * 8);
    o[0] = make_float4(a[0]*inv, a[1]*inv, a[2]*inv, a[3]*inv);
    o[1] = make_float4(a[4]*inv, a[5]*inv, a[6]*inv, a[7]*inv);
}

// =====================================================================
// Kernel 3: second-stage projection (8 -> 8 x3) from feats
// =====================================================================
__global__ __launch_bounds__(256) void proj2_kernel(
    const float* __restrict__ F,
    const float* __restrict__ Wsq, const float* __restrict__ bsq,
    const float* __restrict__ Wsk, const float* __restrict__ bsk,
    const float* __restrict__ Wsv, const float* __restrict__ bsv,
    float* __restrict__ Q, float* __restrict__ K, float* __restrict__ V)
{
    __shared__ float sW[8*24 + 24];
    for (int i = threadIdx.x; i < 8*24 + 24; i += 256) {
        float w;
        if (i < 192) {
            int j = i / 24, c = i % 24;
            w = (c < 8) ? Wsq[j*8 + c] : (c < 16) ? Wsk[j*8 + (c-8)] : Wsv[j*8 + (c-16)];
        } else {
            int c = i - 192;
            w = (c < 8) ? bsq[c] : (c < 16) ? bsk[c-8] : bsv[c-16];
        }
        sW[i] = w;
    }
    __syncthreads();

    int p = blockIdx.x * 256 + threadIdx.x;
    const float* f = F + (size_t)p * 8;
    float fv[8];
    {
        float4 a = ((const float4*)f)[0], c = ((const float4*)f)[1];
        fv[0]=a.x; fv[1]=a.y; fv[2]=a.z; fv[3]=a.w;
        fv[4]=c.x; fv[5]=c.y; fv[6]=c.z; fv[7]=c.w;
    }
    float acc[24];
    #pragma unroll
    for (int o = 0; o < 24; ++o) acc[o] = sW[192 + o];
    #pragma unroll
    for (int j = 0; j < 8; ++j) {
        float fj = fv[j];
        #pragma unroll
        for (int o = 0; o < 24; ++o) acc[o] += fj * sW[j*24 + o];
    }
    size_t base = (size_t)p * 8;
    #pragma unroll
    for (int o = 0; o < 8; ++o) {
        Q[base+o] = acc[o];
        K[base+o] = acc[8+o];
        V[base+o] = acc[16+o];
    }
}

// =====================================================================
// Kernel 5: LayerNorm(8) + proj to 3 + clamped softplus + 8x upsample
// thread per (patch, row-pair): 4 threads share a patch -> 512 blocks
// =====================================================================
__global__ __launch_bounds__(256) void head_kernel(
    const float* __restrict__ S,
    const float* __restrict__ ln_w, const float* __restrict__ ln_b,
    const float* __restrict__ Wp, const float* __restrict__ bp,
    float* __restrict__ out)
{
    int idx = blockIdx.x * 256 + threadIdx.x;   // 0..131071
    int p  = idx >> 2;
    int rq = idx & 3;          // row pair 0..3 -> rows rq*2, rq*2+1
    int b    = p >> 12;
    int pidx = p & 4095;
    int pr = pidx >> 6, pc = pidx & 63;

    const float* s = S + (size_t)p * 8;
    float f[8];
    {
        float4 a = ((const float4*)s)[0], c = ((const float4*)s)[1];
        f[0]=a.x; f[1]=a.y; f[2]=a.z; f[3]=a.w;
        f[4]=c.x; f[5]=c.y; f[6]=c.z; f[7]=c.w;
    }
    float mu = 0.f;
    #pragma unroll
    for (int d = 0; d < 8; ++d) mu += f[d];
    mu *= 0.125f;
    float var = 0.f;
    #pragma unroll
    for (int d = 0; d < 8; ++d) { float t = f[d]-mu; var += t*t; }
    var *= 0.125f;
    float r = rsqrtf(var + 1e-5f);

    float o0 = bp[0], o1 = bp[1], o2 = bp[2];
    #pragma unroll
    for (int d = 0; d < 8; ++d) {
        float n = (f[d]-mu)*r*ln_w[d] + ln_b[d];
        o0 += n*Wp[d*3+0]; o1 += n*Wp[d*3+1]; o2 += n*Wp[d*3+2];
    }
    float o[3] = {o0, o1, o2};
    #pragma unroll
    for (int cix = 0; cix < 3; ++cix) {
        float xx = o[cix];
        float sp = fmaxf(xx, 0.f) + log1pf(expf(-fabsf(xx)));  // stable softplus
        o[cix] = fminf(sp, 6.0f) + 1e-6f;
    }

    float4 f40 = make_float4(o[0], o[1], o[2], o[0]);
    float4 f41 = make_float4(o[1], o[2], o[0], o[1]);
    float4 f42 = make_float4(o[2], o[0], o[1], o[2]);
    float* ob = out + (((size_t)(b*512 + pr*8 + rq*2)) * 512 + (size_t)pc*8) * 3;
    #pragma unroll
    for (int i = 0; i < 2; ++i) {
        float4* row = (float4*)(ob + (size_t)i * 512 * 3);
        row[0]=f40; row[1]=f41; row[2]=f42; row[3]=f40; row[4]=f41; row[5]=f42;
    }
}

// =====================================================================
extern "C" void kernel_launch(void* const* d_in, const int* in_sizes, int n_in,
                              void* d_out, int out_size, void* d_ws, size_t ws_size,
                              hipStream_t stream)
{
    const float* x   = (const float*)d_in[0];
    const float* Wq  = (const float*)d_in[1];
    const float* bq  = (const float*)d_in[2];
    const float* Wk  = (const float*)d_in[3];
    const float* bk  = (const float*)d_in[4];
    const float* Wv  = (const float*)d_in[5];
    const float* bv  = (const float*)d_in[6];
    const float* Wsq = (const float*)d_in[7];
    const float* bsq = (const float*)d_in[8];
    const float* Wsk = (const float*)d_in[9];
    const float* bsk = (const float*)d_in[10];
    const float* Wsv = (const float*)d_in[11];
    const float* bsv = (const float*)d_in[12];
    const float* lnw = (const float*)d_in[13];
    const float* lnb = (const float*)d_in[14];
    const float* Wp  = (const float*)d_in[15];
    const float* bp  = (const float*)d_in[16];
    float* out = (float*)d_out;

    // workspace layout (floats):
    // A,B,C: QKV buffers (262144 each = 1 MB) ; D: feats/sig (1 MB)
    // Pacc: 32768*NC*8 ; Psum: 32768*NC
    float* A = (float*)d_ws;
    float* B = A + 262144;
    float* C = B + 262144;
    float* D = C + 262144;
    float* Pacc = D + 262144;

    qkv_kernel<<<128, 256, 0, stream>>>(x, Wq, bq, Wk, bk, Wv, bv, A, B, C);

    size_t need32 = (size_t)(4*262144 + (size_t)32768*32*9) * 4;
    size_t need16 = (size_t)(4*262144 + (size_t)32768*16*9) * 4;

    if (ws_size >= need32) {
        constexpr int NC = 32;
        float* Psum = Pacc + (size_t)32768*NC*8;
        attn_part_kernel<NC><<<8*4*NC, 256, 0, stream>>>(A, B, C, Pacc, Psum);
        attn_reduce_kernel<NC><<<128, 256, 0, stream>>>(Pacc, Psum, D);
        proj2_kernel<<<128, 256, 0, stream>>>(D, Wsq, bsq, Wsk, bsk, Wsv, bsv, A, B, C);
        attn_part_kernel<NC><<<8*4*NC, 256, 0, stream>>>(A, B, C, Pacc, Psum);
        attn_reduce_kernel<NC><<<128, 256, 0, stream>>>(Pacc, Psum, D);
    } else if (ws_size >= need16) {
        constexpr int NC = 16;
        float* Psum = Pacc + (size_t)32768*NC*8;
        attn_part_kernel<NC><<<8*4*NC, 256, 0, stream>>>(A, B, C, Pacc, Psum);
        attn_reduce_kernel<NC><<<128, 256, 0, stream>>>(Pacc, Psum, D);
        proj2_kernel<<<128, 256, 0, stream>>>(D, Wsq, bsq, Wsk, bsk, Wsv, bsv, A, B, C);
        attn_part_kernel<NC><<<8*4*NC, 256, 0, stream>>>(A, B, C, Pacc, Psum);
        attn_reduce_kernel<NC><<<128, 256, 0, stream>>>(Pacc, Psum, D);
    } else {
        constexpr int NC = 8;
        float* Psum = Pacc + (size_t)32768*NC*8;
        attn_part_kernel<NC><<<8*4*NC, 256, 0, stream>>>(A, B, C, Pacc, Psum);
        attn_reduce_kernel<NC><<<128, 256, 0, stream>>>(Pacc, Psum, D);
        proj2_kernel<<<128, 256, 0, stream>>>(D, Wsq, bsq, Wsk, bsk, Wsv, bsv, A, B, C);
        attn_part_kernel<NC><<<8*4*NC, 256, 0, stream>>>(A, B, C, Pacc, Psum);
        attn_reduce_kernel<NC><<<128, 256, 0, stream>>>(Pacc, Psum, D);
    }

    head_kernel<<<512, 256, 0, stream>>>(D, lnw, lnb, Wp, bp, out);
}

// Round 8
// 254.033 us; speedup vs baseline: 2.5784x; 1.2712x over previous
//
#include <hip/hip_runtime.h>
#include <math.h>
#include <stdint.h>

// ---- problem constants ----
// x: [8,1,512,512] fp32; 8x8 patches -> 4096 patches/batch, pdim=64, HID=8.
// Output [8,512,512,3] fp32.
static constexpr float QSCALE = 0.35355339059327373f * 1.4426950408889634f; // SCALE*log2(e)

typedef _Float16 half8f __attribute__((ext_vector_type(8)));
typedef float f32x4 __attribute__((ext_vector_type(4)));

__device__ __forceinline__ ushort f16_bits(float x) {
    return __builtin_bit_cast(ushort, (_Float16)x);
}
__device__ __forceinline__ float f16_back(ushort u) {
    return (float)__builtin_bit_cast(_Float16, u);
}

// =====================================================================
// Packed-operand writer shared by both prepack kernels.
// Qpack[p]: 32 f16 slots = [q_hi(8), q_lo(8), q_hi(8), 0(8)]   (64 B)
// Kpack[p]: [k_hi(8), k_hi(8), k_lo(8), 0(8)]                  (64 B)
//   -> one 16x16x32 MFMA gives s = qh·kh + ql·kh + qh·kl  (fp32-class)
// VpackT[b][d][key] f16, d<8 = v_d, d=8 = 1.0 (rowsum column)
// =====================================================================
__device__ __forceinline__ void write_packed(
    int p, const float* qv, const float* kv, const float* vv,
    uint* __restrict__ Qpack, uint* __restrict__ Kpack, ushort* __restrict__ VpackT)
{
    uint qw[8], kw[8];
    #pragma unroll
    for (int i = 0; i < 4; ++i) {
        float q0 = qv[2*i], q1 = qv[2*i+1];
        ushort qh0 = f16_bits(q0), qh1 = f16_bits(q1);
        ushort ql0 = f16_bits(q0 - f16_back(qh0));
        ushort ql1 = f16_bits(q1 - f16_back(qh1));
        qw[i]   = (uint)qh0 | ((uint)qh1 << 16);
        qw[4+i] = (uint)ql0 | ((uint)ql1 << 16);
        float k0 = kv[2*i], k1 = kv[2*i+1];
        ushort kh0 = f16_bits(k0), kh1 = f16_bits(k1);
        ushort kl0 = f16_bits(k0 - f16_back(kh0));
        ushort kl1 = f16_bits(k1 - f16_back(kh1));
        kw[i]   = (uint)kh0 | ((uint)kh1 << 16);
        kw[4+i] = (uint)kl0 | ((uint)kl1 << 16);
    }
    uint4* Qp = (uint4*)(Qpack + (size_t)p*16);
    Qp[0] = make_uint4(qw[0],qw[1],qw[2],qw[3]);
    Qp[1] = make_uint4(qw[4],qw[5],qw[6],qw[7]);
    Qp[2] = make_uint4(qw[0],qw[1],qw[2],qw[3]);
    Qp[3] = make_uint4(0,0,0,0);
    uint4* Kp = (uint4*)(Kpack + (size_t)p*16);
    Kp[0] = make_uint4(kw[0],kw[1],kw[2],kw[3]);
    Kp[1] = make_uint4(kw[0],kw[1],kw[2],kw[3]);
    Kp[2] = make_uint4(kw[4],kw[5],kw[6],kw[7]);
    Kp[3] = make_uint4(0,0,0,0);
    int b = p >> 12, pidx = p & 4095;
    #pragma unroll
    for (int d = 0; d < 8; ++d)
        VpackT[((size_t)(b*16 + d))*4096 + pidx] = f16_bits(vv[d]);
    VpackT[((size_t)(b*16 + 8))*4096 + pidx] = 0x3C00; // 1.0
}

// =====================================================================
// Kernel 1: patchify + QKV projection (64 -> 8 x3) + f16 packing
// =====================================================================
__global__ __launch_bounds__(256) void qkv_prepack_kernel(
    const float* __restrict__ x,
    const float* __restrict__ Wq, const float* __restrict__ bq,
    const float* __restrict__ Wk, const float* __restrict__ bk,
    const float* __restrict__ Wv, const float* __restrict__ bv,
    uint* __restrict__ Qpack, uint* __restrict__ Kpack, ushort* __restrict__ VpackT)
{
    __shared__ float sW[64*24 + 24];
    for (int i = threadIdx.x; i < 64*24 + 24; i += 256) {
        float w;
        if (i < 1536) {
            int j = i / 24, c = i % 24;
            w = (c < 8) ? Wq[j*8 + c] : (c < 16) ? Wk[j*8 + (c-8)] : Wv[j*8 + (c-16)];
        } else {
            int c = i - 1536;
            w = (c < 8) ? bq[c] : (c < 16) ? bk[c-8] : bv[c-16];
        }
        sW[i] = w;
    }
    __syncthreads();

    int p = blockIdx.x * 256 + threadIdx.x;
    int b    = p >> 12;
    int pidx = p & 4095;
    int pr = pidx >> 6, pc = pidx & 63;
    const float* xb = x + ((size_t)(b*512 + pr*8)) * 512 + (size_t)pc*8;

    float acc[24];
    #pragma unroll
    for (int o = 0; o < 24; ++o) acc[o] = sW[1536 + o];
    #pragma unroll
    for (int i = 0; i < 8; ++i) {
        float4 a = *(const float4*)(xb + (size_t)i*512);
        float4 c = *(const float4*)(xb + (size_t)i*512 + 4);
        float px[8] = {a.x, a.y, a.z, a.w, c.x, c.y, c.z, c.w};
        #pragma unroll
        for (int jj = 0; jj < 8; ++jj) {
            float pj = px[jj];
            const float* w = &sW[(i*8 + jj)*24];
            #pragma unroll
            for (int o = 0; o < 24; ++o) acc[o] += pj * w[o];
        }
    }
    float qv[8], kv[8], vv[8];
    #pragma unroll
    for (int o = 0; o < 8; ++o) {
        qv[o] = acc[o] * QSCALE;
        kv[o] = acc[8+o];
        vv[o] = acc[16+o];
    }
    write_packed(p, qv, kv, vv, Qpack, Kpack, VpackT);
}

// =====================================================================
// MFMA flash-attention partial pass.
// Per wave: one 16-query tile x 1024-key chunk. Swapped QK (A=K, B=Q)
// puts q in lane&15 of the C output, which IS the PV A-fragment layout:
// no cross-lane movement. Hi/lo f16 packing makes QK and PV fp32-class.
// Per 16-key tile: 2 MFMA + 4 exp2 + ~14 cvt/pack VALU ops.
// K/V staged per-block (4 waves share) through double-buffered LDS.
// Partials (unnormalized O, rowsum) -> existing reduce kernel.
// Grid: 512 q-quads x 4 chunks = 2048 blocks x 256 threads.
// =====================================================================
__global__ __launch_bounds__(256) void attn_mfma_kernel(
    const uint* __restrict__ Qpack, const uint* __restrict__ Kpack,
    const ushort* __restrict__ VpackT,
    float* __restrict__ Pacc, float* __restrict__ Psum)
{
    constexpr int KW = 20;   // LDS u32 words per K row (16 data + 4 pad)
    constexpr int VW = 34;   // LDS u32 words per V d-row (32 data + 2 pad)
    __shared__ uint Kl[2][64*KW];
    __shared__ uint Vl[2][16*VW];

    int tid  = threadIdx.x;
    int lane = tid & 63, wid = tid >> 6;
    int blk  = blockIdx.x;
    int c     = blk & 3;
    int qquad = blk >> 2;
    int qt  = qquad*4 + wid;          // 0..2047 global q-tile
    int b   = qt >> 8;                // batch
    int qg0 = qt * 16;                // global query base
    int kb  = b*4096 + c*1024;        // global key base
    int g = lane >> 4, cl = lane & 15;

    // Q B-fragment: lane holds Q[k_hat=(g*8..g*8+7)][q=cl]
    half8f qfrag = *(const half8f*)(Qpack + ((size_t)(qg0 + cl))*16 + g*4);

    f32x4 acc = {0.f, 0.f, 0.f, 0.f};

    auto stage = [&](int buf, int st) {
        int key = tid >> 2, part = tid & 3;     // K: 16B/thread, 64 keys
        uint4 kd = *(const uint4*)(Kpack + ((size_t)(kb + st*64 + key))*16 + part*4);
        *(uint4*)&Kl[buf][key*KW + part*4] = kd;
        int d = tid >> 4, kk = tid & 15;        // V: 8B/thread (4 keys)
        uint2 vd = *(const uint2*)(VpackT + ((size_t)(b*16 + d))*4096 + (c*1024 + st*64 + kk*4));
        *(uint2*)&Vl[buf][d*VW + kk*2] = vd;
    };

    stage(0, 0);
    __syncthreads();

    for (int st = 0; st < 16; ++st) {
        if (st + 1 < 16) stage((st+1)&1, st+1);
        const uint* Kb = Kl[st&1];
        const uint* Vb = Vl[st&1];
        #pragma unroll
        for (int tt = 0; tt < 4; ++tt) {
            // K A-frag: lane holds K[key=tt*16+cl][k_hat=g*8+j]
            half8f kfrag = *(const half8f*)&Kb[(tt*16 + cl)*KW + g*4];
            f32x4 z = {0.f, 0.f, 0.f, 0.f};
            // S^T tile: lane -> (q=cl, key=tt*16+g*4+r)
            f32x4 s = __builtin_amdgcn_mfma_f32_16x16x32_f16(kfrag, qfrag, z, 0, 0, 0);
            float e0 = exp2f(s[0]), e1 = exp2f(s[1]), e2 = exp2f(s[2]), e3 = exp2f(s[3]);
            ushort h0 = f16_bits(e0), h1 = f16_bits(e1), h2 = f16_bits(e2), h3 = f16_bits(e3);
            ushort l0 = f16_bits(e0 - f16_back(h0)), l1 = f16_bits(e1 - f16_back(h1));
            ushort l2 = f16_bits(e2 - f16_back(h2)), l3 = f16_bits(e3 - f16_back(h3));
            uint4 pu = make_uint4((uint)h0 | ((uint)h1<<16), (uint)h2 | ((uint)h3<<16),
                                  (uint)l0 | ((uint)l1<<16), (uint)l2 | ((uint)l3<<16));
            half8f pfrag = __builtin_bit_cast(half8f, pu);  // [P_hi(4keys), P_lo(4keys)]
            // V B-frag: lane holds V[key=tt*16+g*4+i][d=cl], duplicated for hi/lo slots
            uint2 vu = *(const uint2*)&Vb[cl*VW + tt*8 + g*2];
            uint4 vv = make_uint4(vu.x, vu.y, vu.x, vu.y);
            half8f vfrag = __builtin_bit_cast(half8f, vv);
            // O[q][d] += sum_key (P_hi+P_lo)*V : exact P
            acc = __builtin_amdgcn_mfma_f32_16x16x32_f16(pfrag, vfrag, acc, 0, 0, 0);
        }
        __syncthreads();
    }

    // acc: lane -> O[q = qg0 + g*4 + r][d = cl]; d=8 column = rowsum
    if (cl < 8) {
        #pragma unroll
        for (int r = 0; r < 4; ++r)
            Pacc[((size_t)c*32768 + qg0 + g*4 + r)*8 + cl] = acc[r];
    } else if (cl == 8) {
        #pragma unroll
        for (int r = 0; r < 4; ++r)
            Psum[(size_t)c*32768 + qg0 + g*4 + r] = acc[r];
    }
}

// Reduce NC partials per query -> normalized output [32768 x 8]
template<int NC>
__global__ __launch_bounds__(256) void attn_reduce_kernel(
    const float* __restrict__ Pacc, const float* __restrict__ Psum,
    float* __restrict__ O)
{
    int qg = blockIdx.x * 256 + threadIdx.x;
    float s = 0.f;
    float a[8] = {0,0,0,0,0,0,0,0};
    #pragma unroll
    for (int c = 0; c < NC; ++c) {
        s += Psum[(size_t)c*32768 + qg];
        const float4* pa = (const float4*)(Pacc + ((size_t)c*32768 + qg)*8);
        float4 x0 = pa[0], x1 = pa[1];
        a[0]+=x0.x; a[1]+=x0.y; a[2]+=x0.z; a[3]+=x0.w;
        a[4]+=x1.x; a[5]+=x1.y; a[6]+=x1.z; a[7]+=x1.w;
    }
    float inv = 1.0f / s;
    float4* o = (float4*)(O + (size_t)qg * 8);
    o[0] = make_float4(a[0]*inv, a[1]*inv, a[2]*inv, a[3]*inv);
    o[1] = make_float4(a[4]*inv, a[5]*inv, a[6]*inv, a[7]*inv);
}

// =====================================================================
// Kernel 4: second-stage projection (8 -> 8 x3) + f16 packing
// =====================================================================
__global__ __launch_bounds__(256) void proj2_prepack_kernel(
    const float* __restrict__ F,
    const float* __restrict__ Wsq, const float* __restrict__ bsq,
    const float* __restrict__ Wsk, const float* __restrict__ bsk,
    const float* __restrict__ Wsv, const float* __restrict__ bsv,
    uint* __restrict__ Qpack, uint* __restrict__ Kpack, ushort* __restrict__ VpackT)
{
    __shared__ float sW[8*24 + 24];
    for (int i = threadIdx.x; i < 8*24 + 24; i += 256) {
        float w;
        if (i < 192) {
            int j = i / 24, c = i % 24;
            w = (c < 8) ? Wsq[j*8 + c] : (c < 16) ? Wsk[j*8 + (c-8)] : Wsv[j*8 + (c-16)];
        } else {
            int c = i - 192;
            w = (c < 8) ? bsq[c] : (c < 16) ? bsk[c-8] : bsv[c-16];
        }
        sW[i] = w;
    }
    __syncthreads();

    int p = blockIdx.x * 256 + threadIdx.x;
    const float* f = F + (size_t)p * 8;
    float fv[8];
    {
        float4 a = ((const float4*)f)[0], c = ((const float4*)f)[1];
        fv[0]=a.x; fv[1]=a.y; fv[2]=a.z; fv[3]=a.w;
        fv[4]=c.x; fv[5]=c.y; fv[6]=c.z; fv[7]=c.w;
    }
    float acc[24];
    #pragma unroll
    for (int o = 0; o < 24; ++o) acc[o] = sW[192 + o];
    #pragma unroll
    for (int j = 0; j < 8; ++j) {
        float fj = fv[j];
        #pragma unroll
        for (int o = 0; o < 24; ++o) acc[o] += fj * sW[j*24 + o];
    }
    float qv[8], kv[8], vv[8];
    #pragma unroll
    for (int o = 0; o < 8; ++o) {
        qv[o] = acc[o] * QSCALE;
        kv[o] = acc[8+o];
        vv[o] = acc[16+o];
    }
    write_packed(p, qv, kv, vv, Qpack, Kpack, VpackT);
}

// =====================================================================
// Kernel 6: LayerNorm(8) + proj to 3 + clamped softplus + 8x upsample
// =====================================================================
__global__ __launch_bounds__(256) void head_kernel(
    const float* __restrict__ S,
    const float* __restrict__ ln_w, const float* __restrict__ ln_b,
    const float* __restrict__ Wp, const float* __restrict__ bp,
    float* __restrict__ out)
{
    int idx = blockIdx.x * 256 + threadIdx.x;   // 0..131071
    int p  = idx >> 2;
    int rq = idx & 3;
    int b    = p >> 12;
    int pidx = p & 4095;
    int pr = pidx >> 6, pc = pidx & 63;

    const float* s = S + (size_t)p * 8;
    float f[8];
    {
        float4 a = ((const float4*)s)[0], c = ((const float4*)s)[1];
        f[0]=a.x; f[1]=a.y; f[2]=a.z; f[3]=a.w;
        f[4]=c.x; f[5]=c.y; f[6]=c.z; f[7]=c.w;
    }
    float mu = 0.f;
    #pragma unroll
    for (int d = 0; d < 8; ++d) mu += f[d];
    mu *= 0.125f;
    float var = 0.f;
    #pragma unroll
    for (int d = 0; d < 8; ++d) { float t = f[d]-mu; var += t*t; }
    var *= 0.125f;
    float r = rsqrtf(var + 1e-5f);

    float o0 = bp[0], o1 = bp[1], o2 = bp[2];
    #pragma unroll
    for (int d = 0; d < 8; ++d) {
        float n = (f[d]-mu)*r*ln_w[d] + ln_b[d];
        o0 += n*Wp[d*3+0]; o1 += n*Wp[d*3+1]; o2 += n*Wp[d*3+2];
    }
    float o[3] = {o0, o1, o2};
    #pragma unroll
    for (int cix = 0; cix < 3; ++cix) {
        float xx = o[cix];
        float sp = fmaxf(xx, 0.f) + log1pf(expf(-fabsf(xx)));
        o[cix] = fminf(sp, 6.0f) + 1e-6f;
    }

    float4 f40 = make_float4(o[0], o[1], o[2], o[0]);
    float4 f41 = make_float4(o[1], o[2], o[0], o[1]);
    float4 f42 = make_float4(o[2], o[0], o[1], o[2]);
    float* ob = out + (((size_t)(b*512 + pr*8 + rq*2)) * 512 + (size_t)pc*8) * 3;
    #pragma unroll
    for (int i = 0; i < 2; ++i) {
        float4* row = (float4*)(ob + (size_t)i * 512 * 3);
        row[0]=f40; row[1]=f41; row[2]=f42; row[3]=f40; row[4]=f41; row[5]=f42;
    }
}

// =====================================================================
extern "C" void kernel_launch(void* const* d_in, const int* in_sizes, int n_in,
                              void* d_out, int out_size, void* d_ws, size_t ws_size,
                              hipStream_t stream)
{
    const float* x   = (const float*)d_in[0];
    const float* Wq  = (const float*)d_in[1];
    const float* bq  = (const float*)d_in[2];
    const float* Wk  = (const float*)d_in[3];
    const float* bk  = (const float*)d_in[4];
    const float* Wv  = (const float*)d_in[5];
    const float* bv  = (const float*)d_in[6];
    const float* Wsq = (const float*)d_in[7];
    const float* bsq = (const float*)d_in[8];
    const float* Wsk = (const float*)d_in[9];
    const float* bsk = (const float*)d_in[10];
    const float* Wsv = (const float*)d_in[11];
    const float* bsv = (const float*)d_in[12];
    const float* lnw = (const float*)d_in[13];
    const float* lnb = (const float*)d_in[14];
    const float* Wp  = (const float*)d_in[15];
    const float* bp  = (const float*)d_in[16];
    float* out = (float*)d_out;

    // workspace layout (bytes):
    // Qpack 2MB | Kpack 2MB | VpackT 1MB | D 1MB | Pacc 4MB | Psum 0.5MB
    char* w = (char*)d_ws;
    uint*   Qpack  = (uint*)(w);
    uint*   Kpack  = (uint*)(w + (size_t)(2<<20));
    ushort* VpackT = (ushort*)(w + (size_t)(4<<20));
    float*  D      = (float*)(w + (size_t)(5<<20));
    float*  Pacc   = (float*)(w + (size_t)(6<<20));
    float*  Psum   = (float*)(w + (size_t)(10<<20));

    qkv_prepack_kernel<<<128, 256, 0, stream>>>(x, Wq, bq, Wk, bk, Wv, bv,
                                                Qpack, Kpack, VpackT);
    attn_mfma_kernel<<<2048, 256, 0, stream>>>(Qpack, Kpack, VpackT, Pacc, Psum);
    attn_reduce_kernel<4><<<128, 256, 0, stream>>>(Pacc, Psum, D);
    proj2_prepack_kernel<<<128, 256, 0, stream>>>(D, Wsq, bsq, Wsk, bsk, Wsv, bsv,
                                                  Qpack, Kpack, VpackT);
    attn_mfma_kernel<<<2048, 256, 0, stream>>>(Qpack, Kpack, VpackT, Pacc, Psum);
    attn_reduce_kernel<4><<<128, 256, 0, stream>>>(Pacc, Psum, D);
    head_kernel<<<512, 256, 0, stream>>>(D, lnw, lnb, Wp, bp, out);
}